// Round 1
// 905.317 us; speedup vs baseline: 1.0678x; 1.0678x over previous
//
#include <hip/hip_runtime.h>
#include <cstdint>

#define NTOK  49
#define NHEAD 16
#define HD    32
#define BATCH 2048
#define MTOT  (BATCH*NTOK)                 // 100352
#define SCALE 0.17677669529663687f        // 1/sqrt(32)

typedef float  f32x4  __attribute__((ext_vector_type(4)));
typedef __bf16 bf16x8 __attribute__((ext_vector_type(8)));
typedef __bf16 bf16x4 __attribute__((ext_vector_type(4)));
typedef unsigned int u32;
typedef const u32 __attribute__((address_space(1)))* gas_u32p;
typedef u32 __attribute__((address_space(3)))* las_u32p;

__device__ __forceinline__ void gld16(__bf16* lds, const __bf16* g) {
    __builtin_amdgcn_global_load_lds((gas_u32p)(const void*)g, (las_u32p)(void*)lds, 16, 0, 0);
}

// ---------------- prep kernels (unchanged) ----------------

__global__ __launch_bounds__(256) void cvt_x(const float* __restrict__ x,
                                             __bf16* __restrict__ o, long n) {
    long i = ((long)blockIdx.x * 256 + threadIdx.x) * 8;
    if (i >= n) return;
    float4 a = *(const float4*)(x + i);
    float4 b = *(const float4*)(x + i + 4);
    bf16x8 t;
    t[0] = (__bf16)a.x; t[1] = (__bf16)a.y; t[2] = (__bf16)a.z; t[3] = (__bf16)a.w;
    t[4] = (__bf16)b.x; t[5] = (__bf16)b.y; t[6] = (__bf16)b.z; t[7] = (__bf16)b.w;
    *(bf16x8*)(o + i) = t;
}

__global__ __launch_bounds__(256) void prep_w(const float* __restrict__ qkv_w,
                                              const float* __restrict__ proj_w,
                                              const float* __restrict__ qkv_b,
                                              __bf16* __restrict__ wqkv_t,
                                              __bf16* __restrict__ wp_t,
                                              float* __restrict__ qkvb_s) {
    int idx = blockIdx.x * 256 + threadIdx.x;
    if (idx < 1536 * 512) {
        int nn = idx >> 9, kk = idx & 511;
        float v = qkv_w[kk * 1536 + nn];
        if (nn < 512) v *= SCALE;
        wqkv_t[idx] = (__bf16)v;
    } else if (idx < 1536 * 512 + 512 * 512) {
        int j = idx - 1536 * 512;
        int nn = j >> 9, kk = j & 511;
        wp_t[j] = (__bf16)proj_w[kk * 512 + nn];
    } else if (idx < 1536 * 512 + 512 * 512 + 1536) {
        int n = idx - (1536 * 512 + 512 * 512);
        float v = qkv_b[n];
        if (n < 512) v *= SCALE;
        qkvb_s[n] = v;
    }
}

__global__ __launch_bounds__(256) void prep_addm(const float* __restrict__ mask,
                                                 const float* __restrict__ bias_table,
                                                 float* __restrict__ addm) {
    int idx = blockIdx.x * 256 + threadIdx.x;       // 16*64*16*256 = 4194304 exact
    int rr   = idx & 3;
    int lane = (idx >> 2) & 63;
    int tile = (idx >> 8) & 15;
    int w    = (idx >> 12) & 63;
    int h    = idx >> 18;
    int mt = tile >> 2, nt = tile & 3;
    int g = lane >> 4, c = lane & 15;
    int i = mt * 16 + g * 4 + rr;
    int j = nt * 16 + c;
    float v;
    if (j >= 49)      v = -1e30f;
    else if (i >= 49) v = 0.f;
    else {
        int ai = (i * 37) >> 8, aj = i - ai * 7;
        int bi = (j * 37) >> 8, bj = j - bi * 7;
        int ridx = (ai - bi + 6) * 13 + (aj - bj + 6);
        v = bias_table[ridx * 16 + h] + mask[(w * 49 + i) * 49 + j];
    }
    addm[idx] = v;
}

// ---------------- 256x256 8-phase GEMM, K=512 fixed (8 K-tiles of BK=64) --------------
//
// 8 waves (2M x 4N), per-wave C = 128x64 = acc[8][4] 16x16 frags.
// LDS: A,B each [2 dbuf][2 khalf][256 rows x 32 cols] bf16 = 128 KiB total.
// Half-tile h (global seq): T=h>>2, j=h&3: j0=A-K0, j1=B-K0, j2=A-K1, j3=B-K1;
//   dbuf = T&1. Stage 1 half/phase, 6 halves ahead of compute; vmcnt(8) steady
//   (= 4 halves in flight, exact), never drained to 0 until the last 2 tiles.
// Ledger (phase p = 4T+ph): reads ph0/1 need halves #4T,#4T+1; ph2/3 need +2,+3.
//   Wait at end of ph1/ph3 covers next K-group: issued #(p+5), need #(p+1) ->
//   4 halves outstanding -> vmcnt(8). Slot reuse: stage of half #h at phase h-6
//   is >=1 barrier after the last read of #(h-8) (same slot) for all j. Tail:
//   t6/ph3 -> vmcnt(4), t7/ph1 -> vmcnt(0).
// Swizzle (both-sides, rule #21): logical k-chunk l at phys 16B-slot s=l^((r>>1)&3);
//   staging source pre-swizzled (l = (tid&3)^((tid>>3)&3)), read offset
//   koff = (g^((c>>1)&3))*8 -> 2-way (free) bank access for ds_read_b128.
// B-frags loaded once per K-group (ph0/ph2), reused in ph1/ph3: 24 reads / 64 MFMA.

#define WAIT8 asm volatile("s_waitcnt vmcnt(8)" ::: "memory")
#define WAIT4 asm volatile("s_waitcnt vmcnt(4)" ::: "memory")
#define WAIT0 asm volatile("s_waitcnt vmcnt(0)" ::: "memory")
#define BARR  do { asm volatile("s_barrier" ::: "memory"); \
                   __builtin_amdgcn_sched_barrier(0); } while (0)
#define NOOP  do {} while (0)

#define STAGE_A(sdb, skh, kc) do { \
    gld16(&Asm[sdb][skh][wid * 512],        Ag + (kc)); \
    gld16(&Asm[sdb][skh][4096 + wid * 512], Ag + 128 * 512 + (kc)); } while (0)
#define STAGE_B(sdb, skh, kc) do { \
    gld16(&Bsm[sdb][skh][wid * 512],        Bg + (kc)); \
    gld16(&Bsm[sdb][skh][4096 + wid * 512], Bg + 128 * 512 + (kc)); } while (0)

#define PHASE(db, kh, mh, STG, WT) do { \
    const __bf16* ab = &Asm[db][kh][(mh) ? aoff1 : aoff0]; \
    af[0] = *(const bf16x8*)(ab); \
    af[1] = *(const bf16x8*)(ab + 512); \
    af[2] = *(const bf16x8*)(ab + 1024); \
    af[3] = *(const bf16x8*)(ab + 1536); \
    if (!(mh)) { \
        const __bf16* bb = &Bsm[db][kh][boff]; \
        bfr[0] = *(const bf16x8*)(bb); \
        bfr[1] = *(const bf16x8*)(bb + 512); \
        bfr[2] = *(const bf16x8*)(bb + 1024); \
        bfr[3] = *(const bf16x8*)(bb + 1536); \
    } \
    STG; \
    WT; \
    BARR; \
    __builtin_amdgcn_s_setprio(1); \
    _Pragma("unroll") \
    for (int mf = 0; mf < 4; ++mf) { \
        _Pragma("unroll") \
        for (int nf = 0; nf < 4; ++nf) \
            acc[(mh) * 4 + mf][nf] = __builtin_amdgcn_mfma_f32_16x16x32_bf16( \
                af[mf], bfr[nf], acc[(mh) * 4 + mf][nf], 0, 0, 0); \
    } \
    __builtin_amdgcn_s_setprio(0); \
    __builtin_amdgcn_sched_barrier(0); \
  } while (0)

// MODE 0: fp32 out [M,512] + bias.  MODE 1: qkv split (n<1024 -> qk bf16; else vT).
template <int MODE>
__global__ __launch_bounds__(512, 2)
void gemm256(const __bf16* __restrict__ A, const __bf16* __restrict__ Bt,
             const float* __restrict__ bias, float* __restrict__ outF,
             __bf16* __restrict__ outQK, __bf16* __restrict__ outVT, int NBX) {
    __shared__ __align__(16) __bf16 Asm[2][2][8192];
    __shared__ __align__(16) __bf16 Bsm[2][2][8192];
    const int tid  = threadIdx.x;
    const int wid  = tid >> 6;
    const int lane = tid & 63;
    const int g = lane >> 4, c = lane & 15;
    const int wr = wid >> 2, wc = wid & 3;

    // bijective XCD swizzle (nwg % 8 == 0 for both launches)
    const int nwg = NBX * 392;
    const int lin = blockIdx.y * NBX + blockIdx.x;
    const int sw  = (lin & 7) * (nwg >> 3) + (lin >> 3);
    const int bm  = sw / NBX;
    const int bn  = sw - bm * NBX;
    const long m0 = (long)bm * 256;
    const long n0 = (long)bn * 256;

    // staging: row sr, pre-swizzled logical k-chunk sl
    const int sr = tid >> 2;
    const int sl = (tid & 3) ^ ((tid >> 3) & 3);
    const __bf16* Ag = A  + (m0 + sr) * 512 + sl * 8;
    const __bf16* Bg = Bt + (n0 + sr) * 512 + sl * 8;

    // swizzled read offsets
    const int koff  = (g ^ ((c >> 1) & 3)) * 8;
    const int aoff0 = (wr * 128 + c) * 32 + koff;
    const int aoff1 = aoff0 + 64 * 32;
    const int boff  = (wc * 64 + c) * 32 + koff;

    bf16x8 af[4], bfr[4];
    f32x4 acc[8][4];
#pragma unroll
    for (int i = 0; i < 8; ++i)
#pragma unroll
        for (int j = 0; j < 4; ++j) acc[i][j] = (f32x4){0.f, 0.f, 0.f, 0.f};

    // prologue: halves #0..#5 (12 loads); vmcnt(8) -> #0,#1 complete
    STAGE_A(0, 0, 0);    STAGE_B(0, 0, 0);
    STAGE_A(0, 1, 32);   STAGE_B(0, 1, 32);
    STAGE_A(1, 0, 64);   STAGE_B(1, 0, 64);
    WAIT8;
    BARR;

#pragma unroll 1
    for (int t = 0; t < 6; ++t) {
        const int db = t & 1, odb = db ^ 1;
        const int kA = (t + 1) * 64 + 32;   // A/B-K1 of tile t+1 (other dbuf)
        const int kB = (t + 2) * 64;        // A/B-K0 of tile t+2 (same dbuf)
        PHASE(db, 0, 0, STAGE_A(odb, 1, kA), NOOP);
        PHASE(db, 0, 1, STAGE_B(odb, 1, kA), WAIT8);
        PHASE(db, 1, 0, STAGE_A(db, 0, kB),  NOOP);
        PHASE(db, 1, 1, STAGE_B(db, 0, kB),  WAIT8);
    }
    // t = 6 (dbuf 0): last stages are halves #30,#31 (tile 7 K1)
    PHASE(0, 0, 0, STAGE_A(1, 1, 480), NOOP);
    PHASE(0, 0, 1, STAGE_B(1, 1, 480), WAIT8);
    PHASE(0, 1, 0, NOOP, NOOP);
    PHASE(0, 1, 1, NOOP, WAIT4);
    // t = 7 (dbuf 1): drain
    PHASE(1, 0, 0, NOOP, NOOP);
    PHASE(1, 0, 1, NOOP, WAIT0);
    PHASE(1, 1, 0, NOOP, NOOP);
    PHASE(1, 1, 1, NOOP, NOOP);

    // ---------------- epilogue ----------------
    if (MODE == 0) {
#pragma unroll
        for (int nf = 0; nf < 4; ++nf) {
            const int n = (int)n0 + wc * 64 + nf * 16 + c;
            const float bv = bias[n];
#pragma unroll
            for (int mi = 0; mi < 8; ++mi) {
                const long row0 = m0 + wr * 128 + mi * 16 + g * 4;
#pragma unroll
                for (int rr = 0; rr < 4; ++rr)
                    outF[(row0 + rr) * 512 + n] = acc[mi][nf][rr] + bv;
            }
        }
    } else if (n0 < 1024) {
#pragma unroll
        for (int nf = 0; nf < 4; ++nf) {
            const int n = (int)n0 + wc * 64 + nf * 16 + c;
            const float bv = bias[n];
#pragma unroll
            for (int mi = 0; mi < 8; ++mi) {
                const long row0 = m0 + wr * 128 + mi * 16 + g * 4;
#pragma unroll
                for (int rr = 0; rr < 4; ++rr)
                    outQK[(row0 + rr) * 1024 + n] = (__bf16)(acc[mi][nf][rr] + bv);
            }
        }
    } else {
#pragma unroll
        for (int nf = 0; nf < 4; ++nf) {
            const int n = (int)n0 + wc * 64 + nf * 16 + c;
            const float bv = bias[n];
            const int hh = (n - 1024) >> 5;
            const int dd = (n - 1024) & 31;
#pragma unroll
            for (int mi = 0; mi < 8; ++mi) {
                const int row0 = (int)m0 + wr * 128 + mi * 16 + g * 4;
#pragma unroll
                for (int rr = 0; rr < 4; ++rr) {
                    const int row = row0 + rr;
                    const int b2 = row / 49;
                    const int t2 = row - b2 * 49;
                    outVT[(long)(b2 * 512 + hh * 32 + dd) * 64 + t2] =
                        (__bf16)(acc[mi][nf][rr] + bv);
                }
            }
        }
    }
}

// ---------------- attention: one wave per (b,h), O^T = V^T * P^T (unchanged) ---------

__global__ __launch_bounds__(256)
void attn_k(const __bf16* __restrict__ qk, const __bf16* __restrict__ vT,
            const float* __restrict__ addm, __bf16* __restrict__ ao) {
    __shared__ __bf16 p_all[4][64 * 72];
    const int tid = threadIdx.x;
    const int wid = tid >> 6;
    const int lane = tid & 63;
    const int g = lane >> 4, c = lane & 15;
    const int wv = blockIdx.x * 4 + wid;   // 0..32767
    const int b = wv >> 4, h = wv & 15;
    const int w = b & 63;
    __bf16* psh = p_all[wid];

    const __bf16* base = qk + (long)b * 49 * 1024 + h * 32;

    bf16x8 zero8;
    for (int i = 0; i < 8; ++i) zero8[i] = (__bf16)0.f;

    bf16x8 aq[4], bk[4];
    for (int t4 = 0; t4 < 4; ++t4) {
        int t = t4 * 16 + c;
        const __bf16* p = base + (long)t * 1024 + g * 8;
        bool ok = t < 49;
        aq[t4] = ok ? *(const bf16x8*)p : zero8;
        bk[t4] = ok ? *(const bf16x8*)(p + 512) : zero8;
    }

    const float* am = addm + (long)(h * 64 + w) * 4096;
    f32x4 acc[4][4];
    for (int mt = 0; mt < 4; ++mt)
        for (int nt = 0; nt < 4; ++nt)
            acc[mt][nt] = *(const f32x4*)(am + (mt * 4 + nt) * 256 + lane * 4);

    for (int mt = 0; mt < 4; ++mt)
        for (int nt = 0; nt < 4; ++nt)
            acc[mt][nt] = __builtin_amdgcn_mfma_f32_16x16x32_bf16(aq[mt], bk[nt], acc[mt][nt], 0, 0, 0);

    float linv[4][4];
    for (int mt = 0; mt < 4; ++mt)
        for (int rr = 0; rr < 4; ++rr) {
            float mx = fmaxf(fmaxf(acc[mt][0][rr], acc[mt][1][rr]),
                             fmaxf(acc[mt][2][rr], acc[mt][3][rr]));
            for (int s = 1; s < 16; s <<= 1) mx = fmaxf(mx, __shfl_xor(mx, s));
            float sum = 0.f;
            for (int nt = 0; nt < 4; ++nt) {
                float p = __expf(acc[mt][nt][rr] - mx);
                acc[mt][nt][rr] = p;
                sum += p;
            }
            for (int s = 1; s < 16; s <<= 1) sum += __shfl_xor(sum, s);
            linv[mt][rr] = 1.0f / sum;
        }

    for (int mt = 0; mt < 4; ++mt)
        for (int nt = 0; nt < 4; ++nt)
            for (int rr = 0; rr < 4; ++rr)
                psh[(mt * 16 + g * 4 + rr) * 72 + nt * 16 + c] =
                    (__bf16)(acc[mt][nt][rr] * linv[mt][rr]);

    const __bf16* vb = vT + (long)(b * 16 + h) * 2048;   // 32*64
    bf16x8 av[2][2];
    for (int mt2 = 0; mt2 < 2; ++mt2)
        for (int k2 = 0; k2 < 2; ++k2)
            av[mt2][k2] = *(const bf16x8*)(vb + (mt2 * 16 + c) * 64 + k2 * 32 + g * 8);

    bf16x8 bp[4][2];
    for (int nt2 = 0; nt2 < 4; ++nt2)
        for (int k2 = 0; k2 < 2; ++k2)
            bp[nt2][k2] = *(const bf16x8*)(psh + (nt2 * 16 + c) * 72 + k2 * 32 + g * 8);

    f32x4 oacc[2][4];
    for (int mt2 = 0; mt2 < 2; ++mt2)
        for (int nt2 = 0; nt2 < 4; ++nt2) oacc[mt2][nt2] = (f32x4){0.f, 0.f, 0.f, 0.f};
    for (int mt2 = 0; mt2 < 2; ++mt2)
        for (int nt2 = 0; nt2 < 4; ++nt2)
            for (int k2 = 0; k2 < 2; ++k2)
                oacc[mt2][nt2] = __builtin_amdgcn_mfma_f32_16x16x32_bf16(av[mt2][k2], bp[nt2][k2], oacc[mt2][nt2], 0, 0, 0);

    __bf16* obase = ao + (long)b * 49 * 512 + h * 32;
    for (int nt2 = 0; nt2 < 4; ++nt2) {
        int i = nt2 * 16 + c;
        if (i < 49) {
            for (int mt2 = 0; mt2 < 2; ++mt2) {
                bf16x4 t;
                t[0] = (__bf16)oacc[mt2][nt2][0];
                t[1] = (__bf16)oacc[mt2][nt2][1];
                t[2] = (__bf16)oacc[mt2][nt2][2];
                t[3] = (__bf16)oacc[mt2][nt2][3];
                *(bf16x4*)(obase + (long)i * 512 + mt2 * 16 + g * 4) = t;
            }
        }
    }
}

// ---------------- launch ----------------

extern "C" void kernel_launch(void* const* d_in, const int* in_sizes, int n_in,
                              void* d_out, int out_size, void* d_ws, size_t ws_size,
                              hipStream_t stream) {
    const float* x      = (const float*)d_in[0];
    const float* mask   = (const float*)d_in[1];
    const float* qkv_w  = (const float*)d_in[2];
    const float* qkv_b  = (const float*)d_in[3];
    const float* proj_w = (const float*)d_in[4];
    const float* proj_b = (const float*)d_in[5];
    const float* btab   = (const float*)d_in[6];
    float* out = (float*)d_out;

    char* ws = (char*)d_ws;
    // layout (bytes):
    //   ws_x / ws_ao : 100352*512*2     = 102,760,448  @ 0
    //   ws_qk        : 100352*1024*2    = 205,520,896  @ 102,760,448
    //   wqkv_t       : 1536*512*2       = 1,572,864    @ 308,281,344
    //   wp_t         : 512*512*2        = 524,288      @ 309,854,208
    //   qkvb_s       : 1536*4           = 6,144        @ 310,378,496
    //   addm         : 16*64*16*256*4   = 16,777,216   @ 310,384,640
    //   vT           : 32768*32*64*2    = 134,217,728  @ 327,161,856  (end 461,379,584)
    __bf16* ws_x   = (__bf16*)ws;
    __bf16* ws_ao  = (__bf16*)ws;
    __bf16* ws_qk  = (__bf16*)(ws + 102760448L);
    __bf16* wqkv_t = (__bf16*)(ws + 308281344L);
    __bf16* wp_t   = (__bf16*)(ws + 309854208L);
    float*  qkvb_s = (float*)(ws + 310378496L);
    float*  addm   = (float*)(ws + 310384640L);
    __bf16* ws_vT  = (__bf16*)(ws + 327161856L);

    const long XN = (long)MTOT * 512;   // 51,380,224

    cvt_x<<<25088, 256, 0, stream>>>(x, ws_x, XN);
    prep_w<<<4102, 256, 0, stream>>>(qkv_w, proj_w, qkv_b, wqkv_t, wp_t, qkvb_s);
    prep_addm<<<16384, 256, 0, stream>>>(mask, btab, addm);

    gemm256<1><<<dim3(6, 392), 512, 0, stream>>>(ws_x, wqkv_t, qkvb_s, nullptr, ws_qk, ws_vT, 6);
    attn_k<<<8192, 256, 0, stream>>>(ws_qk, ws_vT, addm, ws_ao);
    gemm256<0><<<dim3(2, 392), 512, 0, stream>>>(ws_ao, wp_t, proj_b, out, nullptr, nullptr, 2);
}